// Round 4
// baseline (2007.115 us; speedup 1.0000x reference)
//
#include <hip/hip_runtime.h>
#include <cstddef>
#include <cstdint>

// Problem constants
#define HH 8
#define FF 512
#define CC 256
#define SS 512
#define BB 64
#define SB (SS*BB)   // 32768

typedef __attribute__((ext_vector_type(4))) float f32x4;
typedef __attribute__((ext_vector_type(8))) short bf16x8;

__device__ __forceinline__ float fast_tanh(float x) {
    float e = __expf(2.0f * x);
    return 1.0f - 2.0f / (e + 1.0f);
}
__device__ __forceinline__ float relu_f(float x) { return fmaxf(x, 0.0f); }

// bf16 bit helpers (round-to-nearest-even)
__device__ __forceinline__ unsigned short f2bf(float x) {
    unsigned u = __float_as_uint(x);
    unsigned r = u + 0x7FFFu + ((u >> 16) & 1u);
    return (unsigned short)(r >> 16);
}
__device__ __forceinline__ float bf2f(unsigned short h) {
    return __uint_as_float(((unsigned)h) << 16);
}

// ---------------------------------------------------------------------------
// P: coalesced tiled transpose+split of w1, wv (512x256 -> [256][512] hi/lo)
//    and W[h] rows 0..C-1 (256x256 -> [h][256][256] hi/lo).
//    Grid: 192 blocks. bid<64: w1/wv tiles; else W tiles.
// ---------------------------------------------------------------------------
__global__ __launch_bounds__(256) void p_trans(
    const float* __restrict__ w1, const float* __restrict__ wv,
    const float* __restrict__ W,
    unsigned short* __restrict__ w1t_hi, unsigned short* __restrict__ w1t_lo,
    unsigned short* __restrict__ wvt_hi, unsigned short* __restrict__ wvt_lo,
    unsigned short* __restrict__ Wt_hi, unsigned short* __restrict__ Wt_lo)
{
    __shared__ float T[64][65];
    const int tid = threadIdx.x;
    const int bid = blockIdx.x;
    const float* src;
    unsigned short *dhi, *dlo;
    int K, kt, nt;
    if (bid < 64) {
        int m = bid >> 5;            // 0: w1, 1: wv
        int t = bid & 31;
        kt = t >> 2; nt = t & 3; K = FF;     // 8 k-tiles x 4 n-tiles
        src = m ? wv : w1;
        dhi = m ? wvt_hi : w1t_hi;
        dlo = m ? wvt_lo : w1t_lo;
    } else {
        int t = bid - 64;            // 0..127
        int h = t >> 4; int tt = t & 15;
        kt = tt >> 2; nt = tt & 3; K = CC;   // 4 x 4 tiles per head
        src = W + (size_t)h * 2 * CC * CC;   // rows 0..C-1, pitch CC
        dhi = Wt_hi + (size_t)h * CC * CC;
        dlo = Wt_lo + (size_t)h * CC * CC;
    }
    const int k0 = kt * 64, n0 = nt * 64;
    #pragma unroll
    for (int jj = 0; jj < 4; ++jj) {
        int i = (tid >> 4) + jj * 16;
        int j = (tid & 15) * 4;
        float4 v = *(const float4*)(src + (size_t)(k0 + i) * CC + n0 + j);
        T[i][j] = v.x; T[i][j+1] = v.y; T[i][j+2] = v.z; T[i][j+3] = v.w;
    }
    __syncthreads();
    #pragma unroll
    for (int jj = 0; jj < 4; ++jj) {
        int n = (tid >> 4) + jj * 16;
        int kq = (tid & 15) * 4;
        unsigned short hv[4], lv[4];
        #pragma unroll
        for (int q = 0; q < 4; ++q) {
            float x = T[kq + q][n];
            unsigned short hx = f2bf(x);
            hv[q] = hx; lv[q] = f2bf(x - bf2f(hx));
        }
        size_t o = (size_t)(n0 + n) * K + k0 + kq;
        *(ushort4*)(dhi + o) = *(ushort4*)hv;
        *(ushort4*)(dlo + o) = *(ushort4*)lv;
    }
}

// ---------------------------------------------------------------------------
// kA: fused  d3 = relu(d2@w1+b1) -> split bf16 hi/lo  AND  tv = bf16(tanh(d2@wv))
// One block per s (64 rows). A-frags loaded direct from global (no A LDS),
// B1/B2 sub-passes share one padded LDS buffer. 3-term split for both GEMMs.
// ---------------------------------------------------------------------------
__global__ __launch_bounds__(256) void kA_d3tv(
    const float* __restrict__ d2,
    const unsigned short* __restrict__ w1t_hi, const unsigned short* __restrict__ w1t_lo,
    const unsigned short* __restrict__ wvt_hi, const unsigned short* __restrict__ wvt_lo,
    const float* __restrict__ b1,
    unsigned short* __restrict__ d3_hi, unsigned short* __restrict__ d3_lo,
    unsigned short* __restrict__ tv)
{
    __shared__ __align__(16) unsigned short B_hi[256][40];   // padded: 2-way free
    __shared__ __align__(16) unsigned short B_lo[256][40];

    const int tid = threadIdx.x;
    const int lane = tid & 63, w = tid >> 6;
    const int s = blockIdx.x;
    const int r0 = s * 64;
    const int m0 = w * 16;
    const int cb = lane & 15, quad = lane >> 4;

    f32x4 acc1[16], acc2[16];
    f32x4 zero = {0.0f, 0.0f, 0.0f, 0.0f};
    #pragma unroll
    for (int t = 0; t < 16; ++t) { acc1[t] = zero; acc2[t] = zero; }

    // this lane's d2 row for A-fragments
    const float* arow = d2 + (size_t)(r0 + m0 + cb) * FF + quad * 8;

    for (int k0 = 0; k0 < FF; k0 += 32) {
        // A-frag: 8 floats of own row, split in regs (no LDS)
        float v[8];
        *(float4*)&v[0] = *(const float4*)(arow + k0);
        *(float4*)&v[4] = *(const float4*)(arow + k0 + 4);
        bf16x8 ah, al;
        #pragma unroll
        for (int j = 0; j < 8; ++j) {
            unsigned short h = f2bf(v[j]);
            ah[j] = (short)h;
            al[j] = (short)f2bf(v[j] - bf2f(h));
        }
        // stage B1 (w1t) chunk: 256n x 32k hi+lo
        #pragma unroll
        for (int j = 0; j < 4; ++j) {
            int idx = j * 256 + tid;
            int n = idx >> 2, kp = (idx & 3) * 8;
            *(bf16x8*)&B_hi[n][kp] = *(const bf16x8*)(w1t_hi + (size_t)n * FF + k0 + kp);
            *(bf16x8*)&B_lo[n][kp] = *(const bf16x8*)(w1t_lo + (size_t)n * FF + k0 + kp);
        }
        __syncthreads();
        #pragma unroll
        for (int t = 0; t < 16; ++t) {
            bf16x8 bh = *(bf16x8*)&B_hi[t * 16 + cb][quad * 8];
            bf16x8 bl = *(bf16x8*)&B_lo[t * 16 + cb][quad * 8];
            acc1[t] = __builtin_amdgcn_mfma_f32_16x16x32_bf16(ah, bh, acc1[t], 0, 0, 0);
            acc1[t] = __builtin_amdgcn_mfma_f32_16x16x32_bf16(ah, bl, acc1[t], 0, 0, 0);
            acc1[t] = __builtin_amdgcn_mfma_f32_16x16x32_bf16(al, bh, acc1[t], 0, 0, 0);
        }
        __syncthreads();
        // stage B2 (wvt) chunk into the same buffer
        #pragma unroll
        for (int j = 0; j < 4; ++j) {
            int idx = j * 256 + tid;
            int n = idx >> 2, kp = (idx & 3) * 8;
            *(bf16x8*)&B_hi[n][kp] = *(const bf16x8*)(wvt_hi + (size_t)n * FF + k0 + kp);
            *(bf16x8*)&B_lo[n][kp] = *(const bf16x8*)(wvt_lo + (size_t)n * FF + k0 + kp);
        }
        __syncthreads();
        #pragma unroll
        for (int t = 0; t < 16; ++t) {
            bf16x8 bh = *(bf16x8*)&B_hi[t * 16 + cb][quad * 8];
            bf16x8 bl = *(bf16x8*)&B_lo[t * 16 + cb][quad * 8];
            acc2[t] = __builtin_amdgcn_mfma_f32_16x16x32_bf16(ah, bh, acc2[t], 0, 0, 0);
            acc2[t] = __builtin_amdgcn_mfma_f32_16x16x32_bf16(ah, bl, acc2[t], 0, 0, 0);
            acc2[t] = __builtin_amdgcn_mfma_f32_16x16x32_bf16(al, bh, acc2[t], 0, 0, 0);
        }
        __syncthreads();
    }
    // epilogue: C-layout col=cb, row=quad*4+r
    #pragma unroll
    for (int t = 0; t < 16; ++t) {
        int c = t * 16 + cb;
        float bias = b1[c];
        #pragma unroll
        for (int r = 0; r < 4; ++r) {
            int b = m0 + quad * 4 + r;
            int gr = r0 + b;
            float val = relu_f(acc1[t][r] + bias);
            unsigned short hv = f2bf(val);
            d3_hi[(size_t)gr * CC + c] = hv;
            d3_lo[(size_t)gr * CC + c] = f2bf(val - bf2f(hv));
            tv[((size_t)b * SS + s) * CC + c] = f2bf(fast_tanh(acc2[t][r]));
        }
    }
}

// ---------------------------------------------------------------------------
// K2a: d4 = relu(d1@w1 + b1)  [B, C]  (fp32 vector, tiny)
// ---------------------------------------------------------------------------
__global__ __launch_bounds__(256) void k2a_d4(
    const float* __restrict__ d1, const float* __restrict__ w1,
    const float* __restrict__ b1, float* __restrict__ d4)
{
    __shared__ float As[16][68];
    __shared__ float Bs[16][68];
    const int n0 = blockIdx.x * 64;
    const int tid = threadIdx.x;
    const int tx = tid & 15, ty = tid >> 4;
    const int lm = tid >> 2, lk4 = (tid & 3) * 4;
    const int bk = tid >> 4, bn4 = (tid & 15) * 4;
    float acc[4][4] = {};
    for (int k0 = 0; k0 < FF; k0 += 16) {
        float4 a = *(const float4*)(d1 + (size_t)lm * FF + k0 + lk4);
        As[lk4+0][lm] = a.x; As[lk4+1][lm] = a.y;
        As[lk4+2][lm] = a.z; As[lk4+3][lm] = a.w;
        *(float4*)&Bs[bk][bn4] = *(const float4*)(w1 + (size_t)(k0+bk)*CC + n0 + bn4);
        __syncthreads();
        #pragma unroll
        for (int kk = 0; kk < 16; ++kk) {
            float4 a4 = *(const float4*)&As[kk][ty*4];
            float4 b4 = *(const float4*)&Bs[kk][tx*4];
            float av[4] = {a4.x, a4.y, a4.z, a4.w};
            float bv[4] = {b4.x, b4.y, b4.z, b4.w};
            #pragma unroll
            for (int i = 0; i < 4; ++i)
                #pragma unroll
                for (int j = 0; j < 4; ++j)
                    acc[i][j] = fmaf(av[i], bv[j], acc[i][j]);
        }
        __syncthreads();
    }
    #pragma unroll
    for (int i = 0; i < 4; ++i) {
        int row = ty*4 + i;
        #pragma unroll
        for (int j = 0; j < 4; ++j)
            d4[(size_t)row*CC + n0 + tx*4 + j] = relu_f(acc[i][j] + b1[n0 + tx*4 + j]);
    }
}

// ---------------------------------------------------------------------------
// K2b: e4[h,b,c] = sum_d d4[b,d] * W[h, C+d, c]  (fp32 vector, tiny)
// ---------------------------------------------------------------------------
__global__ __launch_bounds__(256) void k2b_e4(
    const float* __restrict__ d4, const float* __restrict__ W,
    float* __restrict__ e4)
{
    __shared__ float As[16][68];
    __shared__ float Bs[16][68];
    const int n0 = blockIdx.x * 64;
    const int h  = blockIdx.y;
    const float* Wh = W + ((size_t)h * 2 * CC + CC) * CC;
    const int tid = threadIdx.x;
    const int tx = tid & 15, ty = tid >> 4;
    const int lm = tid >> 2, lk4 = (tid & 3) * 4;
    const int bk = tid >> 4, bn4 = (tid & 15) * 4;
    float acc[4][4] = {};
    for (int k0 = 0; k0 < CC; k0 += 16) {
        float4 a = *(const float4*)(d4 + (size_t)lm * CC + k0 + lk4);
        As[lk4+0][lm] = a.x; As[lk4+1][lm] = a.y;
        As[lk4+2][lm] = a.z; As[lk4+3][lm] = a.w;
        *(float4*)&Bs[bk][bn4] = *(const float4*)(Wh + (size_t)(k0+bk)*CC + n0 + bn4);
        __syncthreads();
        #pragma unroll
        for (int kk = 0; kk < 16; ++kk) {
            float4 a4 = *(const float4*)&As[kk][ty*4];
            float4 b4 = *(const float4*)&Bs[kk][tx*4];
            float av[4] = {a4.x, a4.y, a4.z, a4.w};
            float bv[4] = {b4.x, b4.y, b4.z, b4.w};
            #pragma unroll
            for (int i = 0; i < 4; ++i)
                #pragma unroll
                for (int j = 0; j < 4; ++j)
                    acc[i][j] = fmaf(av[i], bv[j], acc[i][j]);
        }
        __syncthreads();
    }
    #pragma unroll
    for (int i = 0; i < 4; ++i) {
        int b = ty*4 + i;
        #pragma unroll
        for (int j = 0; j < 4; ++j)
            e4[((size_t)h*BB + b)*CC + n0 + tx*4 + j] = acc[i][j];
    }
}

// ---------------------------------------------------------------------------
// kB: per block (one s): A-frags (d3 hi/lo) loaded ONCE into regs, then loop
// 8 heads: stream Wt[h] chunks through padded LDS, MFMA (3-term), epilogue
// tanh + P-dot + shuffle-reduce -> atts[h][b][s].
// ---------------------------------------------------------------------------
__global__ __launch_bounds__(256) void kB_atts(
    const unsigned short* __restrict__ d3_hi, const unsigned short* __restrict__ d3_lo,
    const unsigned short* __restrict__ Wt_hi, const unsigned short* __restrict__ Wt_lo,
    const float* __restrict__ e4, const float* __restrict__ P,
    float* __restrict__ atts)
{
    __shared__ __align__(16) unsigned short B_hi[256][40];
    __shared__ __align__(16) unsigned short B_lo[256][40];

    const int tid = threadIdx.x;
    const int lane = tid & 63, w = tid >> 6;
    const int s = blockIdx.x;
    const int r0 = s * 64;
    const int m0 = w * 16;
    const int cb = lane & 15, quad = lane >> 4;

    // A-fragments for all 8 K-chunks, loaded once, reused for all heads
    bf16x8 ahf[8], alf[8];
    {
        const size_t arow = (size_t)(r0 + m0 + cb) * CC + quad * 8;
        #pragma unroll
        for (int c0 = 0; c0 < 8; ++c0) {
            ahf[c0] = *(const bf16x8*)(d3_hi + arow + c0 * 32);
            alf[c0] = *(const bf16x8*)(d3_lo + arow + c0 * 32);
        }
    }

    f32x4 zero = {0.0f, 0.0f, 0.0f, 0.0f};

    for (int h = 0; h < HH; ++h) {
        const unsigned short* WhH = Wt_hi + (size_t)h * CC * CC;
        const unsigned short* WhL = Wt_lo + (size_t)h * CC * CC;
        f32x4 acc[16];
        #pragma unroll
        for (int t = 0; t < 16; ++t) acc[t] = zero;

        for (int c0 = 0; c0 < 8; ++c0) {       // K chunks of 32
            #pragma unroll
            for (int j = 0; j < 4; ++j) {
                int idx = j * 256 + tid;
                int n = idx >> 2, kp = (idx & 3) * 8;
                *(bf16x8*)&B_hi[n][kp] = *(const bf16x8*)(WhH + (size_t)n * CC + c0 * 32 + kp);
                *(bf16x8*)&B_lo[n][kp] = *(const bf16x8*)(WhL + (size_t)n * CC + c0 * 32 + kp);
            }
            __syncthreads();
            bf16x8 ah = ahf[c0], al = alf[c0];
            #pragma unroll
            for (int t = 0; t < 16; ++t) {
                bf16x8 bh = *(bf16x8*)&B_hi[t * 16 + cb][quad * 8];
                bf16x8 bl = *(bf16x8*)&B_lo[t * 16 + cb][quad * 8];
                acc[t] = __builtin_amdgcn_mfma_f32_16x16x32_bf16(ah, bh, acc[t], 0, 0, 0);
                acc[t] = __builtin_amdgcn_mfma_f32_16x16x32_bf16(ah, bl, acc[t], 0, 0, 0);
                acc[t] = __builtin_amdgcn_mfma_f32_16x16x32_bf16(al, bh, acc[t], 0, 0, 0);
            }
            __syncthreads();
        }
        // epilogue: tanh + P-reduce over c; rows are b
        float part[4] = {0.0f, 0.0f, 0.0f, 0.0f};
        #pragma unroll
        for (int t = 0; t < 16; ++t) {
            int c = t * 16 + cb;
            float p = P[(size_t)h * CC + c];
            #pragma unroll
            for (int r = 0; r < 4; ++r) {
                int b = m0 + quad * 4 + r;
                float u = acc[t][r] + e4[((size_t)h * BB + b) * CC + c];
                part[r] = fmaf(p, fast_tanh(u), part[r]);
            }
        }
        #pragma unroll
        for (int r = 0; r < 4; ++r) {
            float v = part[r];
            v += __shfl_xor(v, 1); v += __shfl_xor(v, 2);
            v += __shfl_xor(v, 4); v += __shfl_xor(v, 8);
            if (cb == 0) {
                int b = m0 + quad * 4 + r;
                atts[((size_t)h * BB + b) * SS + s] = v;
            }
        }
    }
}

// ---------------------------------------------------------------------------
// K4: softmax over s for each (h,b) row of atts
// ---------------------------------------------------------------------------
__global__ __launch_bounds__(256) void k4_softmax(float* __restrict__ atts)
{
    const int row = blockIdx.x;
    float* a = atts + (size_t)row * SS;
    const int tid = threadIdx.x;
    __shared__ float red[256];
    float x0 = a[tid], x1 = a[tid + 256];
    red[tid] = fmaxf(x0, x1);
    __syncthreads();
    for (int w = 128; w > 0; w >>= 1) {
        if (tid < w) red[tid] = fmaxf(red[tid], red[tid + w]);
        __syncthreads();
    }
    float m = red[0];
    __syncthreads();
    float e0 = __expf(x0 - m), e1 = __expf(x1 - m);
    red[tid] = e0 + e1;
    __syncthreads();
    for (int w = 128; w > 0; w >>= 1) {
        if (tid < w) red[tid] += red[tid + w];
        __syncthreads();
    }
    float inv = 1.0f / red[0];
    a[tid] = e0 * inv;
    a[tid + 256] = e1 * inv;
}

// ---------------------------------------------------------------------------
// K5: vs[b][h][c] = sum_s scores[h][b][s] * tv[b][s][c]  (tv bf16)
// Grid (64 b, 4 c-quarters); 256 thr = 64 c x 4 s-stripes.
// ---------------------------------------------------------------------------
__global__ __launch_bounds__(256) void k5_vs(
    const float* __restrict__ scores, const unsigned short* __restrict__ tv,
    float* __restrict__ vs)
{
    __shared__ float sc[HH][SS];          // 16 KB
    __shared__ float red[4][HH][64];      // 8 KB
    const int b = blockIdx.x;
    const int cq = blockIdx.y;
    const int tid = threadIdx.x;
    for (int i = tid; i < HH*SS; i += 256) {
        int h = i >> 9, s = i & 511;
        sc[h][s] = scores[((size_t)h*BB + b)*SS + s];
    }
    __syncthreads();
    const int cl = tid & 63, stripe = tid >> 6;
    const int c = cq * 64 + cl;
    const unsigned short* tvb = tv + ((size_t)b * SS + stripe * 128) * CC + c;
    float acc[HH] = {};
    #pragma unroll 4
    for (int si = 0; si < 128; ++si) {
        float x = bf2f(tvb[(size_t)si * CC]);
        int s = stripe * 128 + si;
        #pragma unroll
        for (int h = 0; h < HH; ++h)
            acc[h] = fmaf(sc[h][s], x, acc[h]);
    }
    #pragma unroll
    for (int h = 0; h < HH; ++h) red[stripe][h][cl] = acc[h];
    __syncthreads();
    if (stripe == 0) {
        #pragma unroll
        for (int h = 0; h < HH; ++h) {
            float v = red[0][h][cl] + red[1][h][cl] + red[2][h][cl] + red[3][h][cl];
            vs[((size_t)b*HH + h)*CC + c] = v;
        }
    }
}

// ---------------------------------------------------------------------------
// K6: out = relu(vs_flat @ wcc + bcc)   [64 x 2048] @ [2048 x 128]
// ---------------------------------------------------------------------------
__global__ __launch_bounds__(256) void k6_out(
    const float* __restrict__ vs, const float* __restrict__ wcc,
    const float* __restrict__ bcc, float* __restrict__ out)
{
    __shared__ float As[16][68];
    __shared__ float Bs[16][68];
    const int n0 = blockIdx.x * 64;
    const int tid = threadIdx.x;
    const int tx = tid & 15, ty = tid >> 4;
    const int lm = tid >> 2, lk4 = (tid & 3) * 4;
    const int bk = tid >> 4, bn4 = (tid & 15) * 4;
    float acc[4][4] = {};
    const int K = HH * CC;  // 2048
    for (int k0 = 0; k0 < K; k0 += 16) {
        float4 a = *(const float4*)(vs + (size_t)lm * K + k0 + lk4);
        As[lk4+0][lm] = a.x; As[lk4+1][lm] = a.y;
        As[lk4+2][lm] = a.z; As[lk4+3][lm] = a.w;
        *(float4*)&Bs[bk][bn4] = *(const float4*)(wcc + (size_t)(k0+bk)*128 + n0 + bn4);
        __syncthreads();
        #pragma unroll
        for (int kk = 0; kk < 16; ++kk) {
            float4 a4 = *(const float4*)&As[kk][ty*4];
            float4 b4 = *(const float4*)&Bs[kk][tx*4];
            float av[4] = {a4.x, a4.y, a4.z, a4.w};
            float bv[4] = {b4.x, b4.y, b4.z, b4.w};
            #pragma unroll
            for (int i = 0; i < 4; ++i)
                #pragma unroll
                for (int j = 0; j < 4; ++j)
                    acc[i][j] = fmaf(av[i], bv[j], acc[i][j]);
        }
        __syncthreads();
    }
    #pragma unroll
    for (int i = 0; i < 4; ++i) {
        int row = ty*4 + i;
        #pragma unroll
        for (int j = 0; j < 4; ++j)
            out[(size_t)row*128 + n0 + tx*4 + j] =
                relu_f(acc[i][j] + bcc[n0 + tx*4 + j]);
    }
}

// ---------------------------------------------------------------------------
extern "C" void kernel_launch(void* const* d_in, const int* in_sizes, int n_in,
                              void* d_out, int out_size, void* d_ws, size_t ws_size,
                              hipStream_t stream)
{
    (void)in_sizes; (void)n_in; (void)out_size; (void)ws_size;
    const float* d1  = (const float*)d_in[0];
    const float* d2  = (const float*)d_in[1];
    const float* w1  = (const float*)d_in[2];
    const float* b1  = (const float*)d_in[3];
    const float* W   = (const float*)d_in[4];
    const float* P   = (const float*)d_in[5];
    const float* wv  = (const float*)d_in[6];
    const float* wcc = (const float*)d_in[7];
    const float* bcc = (const float*)d_in[8];
    float* out = (float*)d_out;

    // Workspace layout (bytes): ~55 MB total
    char* p = (char*)d_ws;
    unsigned short* d3_hi = (unsigned short*)p;  p += (size_t)SB * CC * 2;        // 16.78 MB
    unsigned short* d3_lo = (unsigned short*)p;  p += (size_t)SB * CC * 2;        // 16.78 MB
    unsigned short* tv    = (unsigned short*)p;  p += (size_t)BB * SS * CC * 2;   // 16.78 MB
    unsigned short* w1t_hi = (unsigned short*)p; p += (size_t)CC * FF * 2;        // 256 KB
    unsigned short* w1t_lo = (unsigned short*)p; p += (size_t)CC * FF * 2;
    unsigned short* wvt_hi = (unsigned short*)p; p += (size_t)CC * FF * 2;
    unsigned short* wvt_lo = (unsigned short*)p; p += (size_t)CC * FF * 2;
    unsigned short* Wt_hi  = (unsigned short*)p; p += (size_t)HH * CC * CC * 2;   // 1 MB
    unsigned short* Wt_lo  = (unsigned short*)p; p += (size_t)HH * CC * CC * 2;
    float* d4   = (float*)p;  p += (size_t)BB * CC * 4;        // 64 KB
    float* e4   = (float*)p;  p += (size_t)HH * BB * CC * 4;   // 512 KB
    float* atts = (float*)p;  p += (size_t)HH * BB * SS * 4;   // 1 MB
    float* vs   = (float*)p;  p += (size_t)BB * HH * CC * 4;   // 512 KB

    p_trans  <<<dim3(192),          256, 0, stream>>>(w1, wv, W,
                                       w1t_hi, w1t_lo, wvt_hi, wvt_lo, Wt_hi, Wt_lo);
    k2a_d4   <<<dim3(CC/64),        256, 0, stream>>>(d1, w1, b1, d4);
    k2b_e4   <<<dim3(CC/64, HH),    256, 0, stream>>>(d4, W, e4);
    kA_d3tv  <<<dim3(SS),           256, 0, stream>>>(d2, w1t_hi, w1t_lo,
                                       wvt_hi, wvt_lo, b1, d3_hi, d3_lo, tv);
    kB_atts  <<<dim3(SS),           256, 0, stream>>>(d3_hi, d3_lo, Wt_hi, Wt_lo,
                                       e4, P, atts);
    k4_softmax<<<dim3(HH*BB),       256, 0, stream>>>(atts);
    k5_vs    <<<dim3(BB, 4),        256, 0, stream>>>(atts, tv, vs);
    k6_out   <<<dim3(128/64),       256, 0, stream>>>(vs, wcc, bcc, out);
}

// Round 5
// 532.529 us; speedup vs baseline: 3.7690x; 3.7690x over previous
//
#include <hip/hip_runtime.h>
#include <cstddef>
#include <cstdint>

// Problem constants
#define HH 8
#define FF 512
#define CC 256
#define SS 512
#define BB 64
#define SB (SS*BB)   // 32768

typedef __attribute__((ext_vector_type(4))) float f32x4;
typedef __attribute__((ext_vector_type(8))) short bf16x8;

__device__ __forceinline__ float fast_tanh(float x) {
    float e = __expf(2.0f * x);
    return 1.0f - 2.0f / (e + 1.0f);
}
__device__ __forceinline__ float relu_f(float x) { return fmaxf(x, 0.0f); }

// bf16 bit helpers (round-to-nearest-even)
__device__ __forceinline__ unsigned short f2bf(float x) {
    unsigned u = __float_as_uint(x);
    unsigned r = u + 0x7FFFu + ((u >> 16) & 1u);
    return (unsigned short)(r >> 16);
}
__device__ __forceinline__ float bf2f(unsigned short h) {
    return __uint_as_float(((unsigned)h) << 16);
}

// ---------------------------------------------------------------------------
// P: coalesced tiled transpose+split of w1, wv (512x256 -> [256][512] hi/lo)
//    and W[h] rows 0..C-1 (256x256 -> [h][256][256] hi/lo).
// ---------------------------------------------------------------------------
__global__ __launch_bounds__(256) void p_trans(
    const float* __restrict__ w1, const float* __restrict__ wv,
    const float* __restrict__ W,
    unsigned short* __restrict__ w1t_hi, unsigned short* __restrict__ w1t_lo,
    unsigned short* __restrict__ wvt_hi, unsigned short* __restrict__ wvt_lo,
    unsigned short* __restrict__ Wt_hi, unsigned short* __restrict__ Wt_lo)
{
    __shared__ float T[64][65];
    const int tid = threadIdx.x;
    const int bid = blockIdx.x;
    const float* src;
    unsigned short *dhi, *dlo;
    int K, kt, nt;
    if (bid < 64) {
        int m = bid >> 5;            // 0: w1, 1: wv
        int t = bid & 31;
        kt = t >> 2; nt = t & 3; K = FF;     // 8 k-tiles x 4 n-tiles
        src = m ? wv : w1;
        dhi = m ? wvt_hi : w1t_hi;
        dlo = m ? wvt_lo : w1t_lo;
    } else {
        int t = bid - 64;            // 0..127
        int h = t >> 4; int tt = t & 15;
        kt = tt >> 2; nt = tt & 3; K = CC;   // 4 x 4 tiles per head
        src = W + (size_t)h * 2 * CC * CC;   // rows 0..C-1, pitch CC
        dhi = Wt_hi + (size_t)h * CC * CC;
        dlo = Wt_lo + (size_t)h * CC * CC;
    }
    const int k0 = kt * 64, n0 = nt * 64;
    #pragma unroll
    for (int jj = 0; jj < 4; ++jj) {
        int i = (tid >> 4) + jj * 16;
        int j = (tid & 15) * 4;
        float4 v = *(const float4*)(src + (size_t)(k0 + i) * CC + n0 + j);
        T[i][j] = v.x; T[i][j+1] = v.y; T[i][j+2] = v.z; T[i][j+3] = v.w;
    }
    __syncthreads();
    #pragma unroll
    for (int jj = 0; jj < 4; ++jj) {
        int n = (tid >> 4) + jj * 16;
        int kq = (tid & 15) * 4;
        unsigned short hv[4], lv[4];
        #pragma unroll
        for (int q = 0; q < 4; ++q) {
            float x = T[kq + q][n];
            unsigned short hx = f2bf(x);
            hv[q] = hx; lv[q] = f2bf(x - bf2f(hx));
        }
        size_t o = (size_t)(n0 + n) * K + k0 + kq;
        *(ushort4*)(dhi + o) = *(ushort4*)hv;
        *(ushort4*)(dlo + o) = *(ushort4*)lv;
    }
}

// ---------------------------------------------------------------------------
// k1a: d3 = relu(d2@w1 + b1) -> split bf16 hi/lo [SB][C].
// One block per s (64 rows x full N=256). A-frags direct from global (8 VGPR
// live per chunk), B staged in padded LDS ([40] rows: 2-way conflicts = free).
// ---------------------------------------------------------------------------
__global__ __launch_bounds__(256) void k1a_d3(
    const float* __restrict__ d2,
    const unsigned short* __restrict__ w1t_hi, const unsigned short* __restrict__ w1t_lo,
    const float* __restrict__ b1,
    unsigned short* __restrict__ d3_hi, unsigned short* __restrict__ d3_lo)
{
    __shared__ __align__(16) unsigned short B_hi[256][40];
    __shared__ __align__(16) unsigned short B_lo[256][40];

    const int tid = threadIdx.x;
    const int lane = tid & 63, w = tid >> 6;
    const int r0 = blockIdx.x * 64;
    const int m0 = w * 16;
    const int cb = lane & 15, quad = lane >> 4;

    f32x4 acc[16];
    f32x4 zero = {0.0f, 0.0f, 0.0f, 0.0f};
    #pragma unroll
    for (int t = 0; t < 16; ++t) acc[t] = zero;

    const float* arow = d2 + (size_t)(r0 + m0 + cb) * FF + quad * 8;

    for (int k0 = 0; k0 < FF; k0 += 32) {
        float v[8];
        *(float4*)&v[0] = *(const float4*)(arow + k0);
        *(float4*)&v[4] = *(const float4*)(arow + k0 + 4);
        bf16x8 ah, al;
        #pragma unroll
        for (int j = 0; j < 8; ++j) {
            unsigned short h = f2bf(v[j]);
            ah[j] = (short)h;
            al[j] = (short)f2bf(v[j] - bf2f(h));
        }
        #pragma unroll
        for (int j = 0; j < 4; ++j) {
            int idx = j * 256 + tid;
            int n = idx >> 2, kp = (idx & 3) * 8;
            *(bf16x8*)&B_hi[n][kp] = *(const bf16x8*)(w1t_hi + (size_t)n * FF + k0 + kp);
            *(bf16x8*)&B_lo[n][kp] = *(const bf16x8*)(w1t_lo + (size_t)n * FF + k0 + kp);
        }
        __syncthreads();
        #pragma unroll
        for (int t = 0; t < 16; ++t) {
            bf16x8 bh = *(bf16x8*)&B_hi[t * 16 + cb][quad * 8];
            bf16x8 bl = *(bf16x8*)&B_lo[t * 16 + cb][quad * 8];
            acc[t] = __builtin_amdgcn_mfma_f32_16x16x32_bf16(ah, bh, acc[t], 0, 0, 0);
            acc[t] = __builtin_amdgcn_mfma_f32_16x16x32_bf16(ah, bl, acc[t], 0, 0, 0);
            acc[t] = __builtin_amdgcn_mfma_f32_16x16x32_bf16(al, bh, acc[t], 0, 0, 0);
        }
        __syncthreads();
    }
    #pragma unroll
    for (int t = 0; t < 16; ++t) {
        int c = t * 16 + cb;
        float bias = b1[c];
        #pragma unroll
        for (int r = 0; r < 4; ++r) {
            int gr = r0 + m0 + quad * 4 + r;
            float val = relu_f(acc[t][r] + bias);
            unsigned short hv = f2bf(val);
            d3_hi[(size_t)gr * CC + c] = hv;
            d3_lo[(size_t)gr * CC + c] = f2bf(val - bf2f(hv));
        }
    }
}

// ---------------------------------------------------------------------------
// k1b: tv[b][s][c] = bf16(tanh(d2@wv)). Same structure as k1a.
// ---------------------------------------------------------------------------
__global__ __launch_bounds__(256) void k1b_tv(
    const float* __restrict__ d2,
    const unsigned short* __restrict__ wvt_hi, const unsigned short* __restrict__ wvt_lo,
    unsigned short* __restrict__ tv)
{
    __shared__ __align__(16) unsigned short B_hi[256][40];
    __shared__ __align__(16) unsigned short B_lo[256][40];

    const int tid = threadIdx.x;
    const int lane = tid & 63, w = tid >> 6;
    const int s = blockIdx.x;
    const int r0 = s * 64;
    const int m0 = w * 16;
    const int cb = lane & 15, quad = lane >> 4;

    f32x4 acc[16];
    f32x4 zero = {0.0f, 0.0f, 0.0f, 0.0f};
    #pragma unroll
    for (int t = 0; t < 16; ++t) acc[t] = zero;

    const float* arow = d2 + (size_t)(r0 + m0 + cb) * FF + quad * 8;

    for (int k0 = 0; k0 < FF; k0 += 32) {
        float v[8];
        *(float4*)&v[0] = *(const float4*)(arow + k0);
        *(float4*)&v[4] = *(const float4*)(arow + k0 + 4);
        bf16x8 ah, al;
        #pragma unroll
        for (int j = 0; j < 8; ++j) {
            unsigned short h = f2bf(v[j]);
            ah[j] = (short)h;
            al[j] = (short)f2bf(v[j] - bf2f(h));
        }
        #pragma unroll
        for (int j = 0; j < 4; ++j) {
            int idx = j * 256 + tid;
            int n = idx >> 2, kp = (idx & 3) * 8;
            *(bf16x8*)&B_hi[n][kp] = *(const bf16x8*)(wvt_hi + (size_t)n * FF + k0 + kp);
            *(bf16x8*)&B_lo[n][kp] = *(const bf16x8*)(wvt_lo + (size_t)n * FF + k0 + kp);
        }
        __syncthreads();
        #pragma unroll
        for (int t = 0; t < 16; ++t) {
            bf16x8 bh = *(bf16x8*)&B_hi[t * 16 + cb][quad * 8];
            bf16x8 bl = *(bf16x8*)&B_lo[t * 16 + cb][quad * 8];
            acc[t] = __builtin_amdgcn_mfma_f32_16x16x32_bf16(ah, bh, acc[t], 0, 0, 0);
            acc[t] = __builtin_amdgcn_mfma_f32_16x16x32_bf16(ah, bl, acc[t], 0, 0, 0);
            acc[t] = __builtin_amdgcn_mfma_f32_16x16x32_bf16(al, bh, acc[t], 0, 0, 0);
        }
        __syncthreads();
    }
    #pragma unroll
    for (int t = 0; t < 16; ++t) {
        int c = t * 16 + cb;
        #pragma unroll
        for (int r = 0; r < 4; ++r) {
            int b = m0 + quad * 4 + r;
            tv[((size_t)b * SS + s) * CC + c] = f2bf(fast_tanh(acc[t][r]));
        }
    }
}

// ---------------------------------------------------------------------------
// K2a: d4 = relu(d1@w1 + b1)  [B, C]  (fp32 vector, tiny)
// ---------------------------------------------------------------------------
__global__ __launch_bounds__(256) void k2a_d4(
    const float* __restrict__ d1, const float* __restrict__ w1,
    const float* __restrict__ b1, float* __restrict__ d4)
{
    __shared__ float As[16][68];
    __shared__ float Bs[16][68];
    const int n0 = blockIdx.x * 64;
    const int tid = threadIdx.x;
    const int tx = tid & 15, ty = tid >> 4;
    const int lm = tid >> 2, lk4 = (tid & 3) * 4;
    const int bk = tid >> 4, bn4 = (tid & 15) * 4;
    float acc[4][4] = {};
    for (int k0 = 0; k0 < FF; k0 += 16) {
        float4 a = *(const float4*)(d1 + (size_t)lm * FF + k0 + lk4);
        As[lk4+0][lm] = a.x; As[lk4+1][lm] = a.y;
        As[lk4+2][lm] = a.z; As[lk4+3][lm] = a.w;
        *(float4*)&Bs[bk][bn4] = *(const float4*)(w1 + (size_t)(k0+bk)*CC + n0 + bn4);
        __syncthreads();
        #pragma unroll
        for (int kk = 0; kk < 16; ++kk) {
            float4 a4 = *(const float4*)&As[kk][ty*4];
            float4 b4 = *(const float4*)&Bs[kk][tx*4];
            float av[4] = {a4.x, a4.y, a4.z, a4.w};
            float bv[4] = {b4.x, b4.y, b4.z, b4.w};
            #pragma unroll
            for (int i = 0; i < 4; ++i)
                #pragma unroll
                for (int j = 0; j < 4; ++j)
                    acc[i][j] = fmaf(av[i], bv[j], acc[i][j]);
        }
        __syncthreads();
    }
    #pragma unroll
    for (int i = 0; i < 4; ++i) {
        int row = ty*4 + i;
        #pragma unroll
        for (int j = 0; j < 4; ++j)
            d4[(size_t)row*CC + n0 + tx*4 + j] = relu_f(acc[i][j] + b1[n0 + tx*4 + j]);
    }
}

// ---------------------------------------------------------------------------
// K2b: e4[h,b,c] = sum_d d4[b,d] * W[h, C+d, c]  (fp32 vector, tiny)
// ---------------------------------------------------------------------------
__global__ __launch_bounds__(256) void k2b_e4(
    const float* __restrict__ d4, const float* __restrict__ W,
    float* __restrict__ e4)
{
    __shared__ float As[16][68];
    __shared__ float Bs[16][68];
    const int n0 = blockIdx.x * 64;
    const int h  = blockIdx.y;
    const float* Wh = W + ((size_t)h * 2 * CC + CC) * CC;
    const int tid = threadIdx.x;
    const int tx = tid & 15, ty = tid >> 4;
    const int lm = tid >> 2, lk4 = (tid & 3) * 4;
    const int bk = tid >> 4, bn4 = (tid & 15) * 4;
    float acc[4][4] = {};
    for (int k0 = 0; k0 < CC; k0 += 16) {
        float4 a = *(const float4*)(d4 + (size_t)lm * CC + k0 + lk4);
        As[lk4+0][lm] = a.x; As[lk4+1][lm] = a.y;
        As[lk4+2][lm] = a.z; As[lk4+3][lm] = a.w;
        *(float4*)&Bs[bk][bn4] = *(const float4*)(Wh + (size_t)(k0+bk)*CC + n0 + bn4);
        __syncthreads();
        #pragma unroll
        for (int kk = 0; kk < 16; ++kk) {
            float4 a4 = *(const float4*)&As[kk][ty*4];
            float4 b4 = *(const float4*)&Bs[kk][tx*4];
            float av[4] = {a4.x, a4.y, a4.z, a4.w};
            float bv[4] = {b4.x, b4.y, b4.z, b4.w};
            #pragma unroll
            for (int i = 0; i < 4; ++i)
                #pragma unroll
                for (int j = 0; j < 4; ++j)
                    acc[i][j] = fmaf(av[i], bv[j], acc[i][j]);
        }
        __syncthreads();
    }
    #pragma unroll
    for (int i = 0; i < 4; ++i) {
        int b = ty*4 + i;
        #pragma unroll
        for (int j = 0; j < 4; ++j)
            e4[((size_t)h*BB + b)*CC + n0 + tx*4 + j] = acc[i][j];
    }
}

// ---------------------------------------------------------------------------
// k3: atts[h,b,s] = sum_c P[h,c]*tanh((d3@Wt[h])[row,c] + e4[h,b,c]).
// Grid (SS, HH): one s + one head per block (4096 blocks). A-frags direct
// from global per chunk; Wt[h] staged through padded LDS. 3-term split.
// ---------------------------------------------------------------------------
__global__ __launch_bounds__(256) void k3_atts(
    const unsigned short* __restrict__ d3_hi, const unsigned short* __restrict__ d3_lo,
    const unsigned short* __restrict__ Wt_hi, const unsigned short* __restrict__ Wt_lo,
    const float* __restrict__ e4, const float* __restrict__ P,
    float* __restrict__ atts)
{
    __shared__ __align__(16) unsigned short B_hi[256][40];
    __shared__ __align__(16) unsigned short B_lo[256][40];

    const int tid = threadIdx.x;
    const int lane = tid & 63, w = tid >> 6;
    const int h = blockIdx.y;
    const int s = blockIdx.x;
    const int r0 = s * 64;
    const int m0 = w * 16;
    const int cb = lane & 15, quad = lane >> 4;

    const unsigned short* WhH = Wt_hi + (size_t)h * CC * CC;
    const unsigned short* WhL = Wt_lo + (size_t)h * CC * CC;
    const size_t arow = (size_t)(r0 + m0 + cb) * CC + quad * 8;

    f32x4 acc[16];
    f32x4 zero = {0.0f, 0.0f, 0.0f, 0.0f};
    #pragma unroll
    for (int t = 0; t < 16; ++t) acc[t] = zero;

    for (int k0 = 0; k0 < CC; k0 += 32) {
        bf16x8 ah = *(const bf16x8*)(d3_hi + arow + k0);
        bf16x8 al = *(const bf16x8*)(d3_lo + arow + k0);
        #pragma unroll
        for (int j = 0; j < 4; ++j) {
            int idx = j * 256 + tid;
            int n = idx >> 2, kp = (idx & 3) * 8;
            *(bf16x8*)&B_hi[n][kp] = *(const bf16x8*)(WhH + (size_t)n * CC + k0 + kp);
            *(bf16x8*)&B_lo[n][kp] = *(const bf16x8*)(WhL + (size_t)n * CC + k0 + kp);
        }
        __syncthreads();
        #pragma unroll
        for (int t = 0; t < 16; ++t) {
            bf16x8 bh = *(bf16x8*)&B_hi[t * 16 + cb][quad * 8];
            bf16x8 bl = *(bf16x8*)&B_lo[t * 16 + cb][quad * 8];
            acc[t] = __builtin_amdgcn_mfma_f32_16x16x32_bf16(ah, bh, acc[t], 0, 0, 0);
            acc[t] = __builtin_amdgcn_mfma_f32_16x16x32_bf16(ah, bl, acc[t], 0, 0, 0);
            acc[t] = __builtin_amdgcn_mfma_f32_16x16x32_bf16(al, bh, acc[t], 0, 0, 0);
        }
        __syncthreads();
    }
    // epilogue: tanh + P-reduce over c (cols); rows are b
    float part[4] = {0.0f, 0.0f, 0.0f, 0.0f};
    #pragma unroll
    for (int t = 0; t < 16; ++t) {
        int c = t * 16 + cb;
        float p = P[(size_t)h * CC + c];
        #pragma unroll
        for (int r = 0; r < 4; ++r) {
            int b = m0 + quad * 4 + r;
            float u = acc[t][r] + e4[((size_t)h * BB + b) * CC + c];
            part[r] = fmaf(p, fast_tanh(u), part[r]);
        }
    }
    #pragma unroll
    for (int r = 0; r < 4; ++r) {
        float v = part[r];
        v += __shfl_xor(v, 1); v += __shfl_xor(v, 2);
        v += __shfl_xor(v, 4); v += __shfl_xor(v, 8);
        if (cb == 0) {
            int b = m0 + quad * 4 + r;
            atts[((size_t)h * BB + b) * SS + s] = v;
        }
    }
}

// ---------------------------------------------------------------------------
// K4: softmax over s for each (h,b) row of atts
// ---------------------------------------------------------------------------
__global__ __launch_bounds__(256) void k4_softmax(float* __restrict__ atts)
{
    const int row = blockIdx.x;
    float* a = atts + (size_t)row * SS;
    const int tid = threadIdx.x;
    __shared__ float red[256];
    float x0 = a[tid], x1 = a[tid + 256];
    red[tid] = fmaxf(x0, x1);
    __syncthreads();
    for (int w = 128; w > 0; w >>= 1) {
        if (tid < w) red[tid] = fmaxf(red[tid], red[tid + w]);
        __syncthreads();
    }
    float m = red[0];
    __syncthreads();
    float e0 = __expf(x0 - m), e1 = __expf(x1 - m);
    red[tid] = e0 + e1;
    __syncthreads();
    for (int w = 128; w > 0; w >>= 1) {
        if (tid < w) red[tid] += red[tid + w];
        __syncthreads();
    }
    float inv = 1.0f / red[0];
    a[tid] = e0 * inv;
    a[tid + 256] = e1 * inv;
}

// ---------------------------------------------------------------------------
// K5: vs[b][h][c] = sum_s scores[h][b][s] * tv[b][s][c]  (tv bf16)
// Grid (64 b, 4 c-quarters); 256 thr = 64 c x 4 s-stripes.
// ---------------------------------------------------------------------------
__global__ __launch_bounds__(256) void k5_vs(
    const float* __restrict__ scores, const unsigned short* __restrict__ tv,
    float* __restrict__ vs)
{
    __shared__ float sc[HH][SS];          // 16 KB
    __shared__ float red[4][HH][64];      // 8 KB
    const int b = blockIdx.x;
    const int cq = blockIdx.y;
    const int tid = threadIdx.x;
    for (int i = tid; i < HH*SS; i += 256) {
        int h = i >> 9, s = i & 511;
        sc[h][s] = scores[((size_t)h*BB + b)*SS + s];
    }
    __syncthreads();
    const int cl = tid & 63, stripe = tid >> 6;
    const int c = cq * 64 + cl;
    const unsigned short* tvb = tv + ((size_t)b * SS + stripe * 128) * CC + c;
    float acc[HH] = {};
    #pragma unroll 4
    for (int si = 0; si < 128; ++si) {
        float x = bf2f(tvb[(size_t)si * CC]);
        int s = stripe * 128 + si;
        #pragma unroll
        for (int h = 0; h < HH; ++h)
            acc[h] = fmaf(sc[h][s], x, acc[h]);
    }
    #pragma unroll
    for (int h = 0; h < HH; ++h) red[stripe][h][cl] = acc[h];
    __syncthreads();
    if (stripe == 0) {
        #pragma unroll
        for (int h = 0; h < HH; ++h) {
            float v = red[0][h][cl] + red[1][h][cl] + red[2][h][cl] + red[3][h][cl];
            vs[((size_t)b*HH + h)*CC + c] = v;
        }
    }
}

// ---------------------------------------------------------------------------
// K6: out = relu(vs_flat @ wcc + bcc)   [64 x 2048] @ [2048 x 128]
// ---------------------------------------------------------------------------
__global__ __launch_bounds__(256) void k6_out(
    const float* __restrict__ vs, const float* __restrict__ wcc,
    const float* __restrict__ bcc, float* __restrict__ out)
{
    __shared__ float As[16][68];
    __shared__ float Bs[16][68];
    const int n0 = blockIdx.x * 64;
    const int tid = threadIdx.x;
    const int tx = tid & 15, ty = tid >> 4;
    const int lm = tid >> 2, lk4 = (tid & 3) * 4;
    const int bk = tid >> 4, bn4 = (tid & 15) * 4;
    float acc[4][4] = {};
    const int K = HH * CC;  // 2048
    for (int k0 = 0; k0 < K; k0 += 16) {
        float4 a = *(const float4*)(vs + (size_t)lm * K + k0 + lk4);
        As[lk4+0][lm] = a.x; As[lk4+1][lm] = a.y;
        As[lk4+2][lm] = a.z; As[lk4+3][lm] = a.w;
        *(float4*)&Bs[bk][bn4] = *(const float4*)(wcc + (size_t)(k0+bk)*128 + n0 + bn4);
        __syncthreads();
        #pragma unroll
        for (int kk = 0; kk < 16; ++kk) {
            float4 a4 = *(const float4*)&As[kk][ty*4];
            float4 b4 = *(const float4*)&Bs[kk][tx*4];
            float av[4] = {a4.x, a4.y, a4.z, a4.w};
            float bv[4] = {b4.x, b4.y, b4.z, b4.w};
            #pragma unroll
            for (int i = 0; i < 4; ++i)
                #pragma unroll
                for (int j = 0; j < 4; ++j)
                    acc[i][j] = fmaf(av[i], bv[j], acc[i][j]);
        }
        __syncthreads();
    }
    #pragma unroll
    for (int i = 0; i < 4; ++i) {
        int row = ty*4 + i;
        #pragma unroll
        for (int j = 0; j < 4; ++j)
            out[(size_t)row*128 + n0 + tx*4 + j] =
                relu_f(acc[i][j] + bcc[n0 + tx*4 + j]);
    }
}

// ---------------------------------------------------------------------------
extern "C" void kernel_launch(void* const* d_in, const int* in_sizes, int n_in,
                              void* d_out, int out_size, void* d_ws, size_t ws_size,
                              hipStream_t stream)
{
    (void)in_sizes; (void)n_in; (void)out_size; (void)ws_size;
    const float* d1  = (const float*)d_in[0];
    const float* d2  = (const float*)d_in[1];
    const float* w1  = (const float*)d_in[2];
    const float* b1  = (const float*)d_in[3];
    const float* W   = (const float*)d_in[4];
    const float* P   = (const float*)d_in[5];
    const float* wv  = (const float*)d_in[6];
    const float* wcc = (const float*)d_in[7];
    const float* bcc = (const float*)d_in[8];
    float* out = (float*)d_out;

    // Workspace layout (bytes): ~55 MB total
    char* p = (char*)d_ws;
    unsigned short* d3_hi = (unsigned short*)p;  p += (size_t)SB * CC * 2;        // 16.78 MB
    unsigned short* d3_lo = (unsigned short*)p;  p += (size_t)SB * CC * 2;        // 16.78 MB
    unsigned short* tv    = (unsigned short*)p;  p += (size_t)BB * SS * CC * 2;   // 16.78 MB
    unsigned short* w1t_hi = (unsigned short*)p; p += (size_t)CC * FF * 2;        // 256 KB
    unsigned short* w1t_lo = (unsigned short*)p; p += (size_t)CC * FF * 2;
    unsigned short* wvt_hi = (unsigned short*)p; p += (size_t)CC * FF * 2;
    unsigned short* wvt_lo = (unsigned short*)p; p += (size_t)CC * FF * 2;
    unsigned short* Wt_hi  = (unsigned short*)p; p += (size_t)HH * CC * CC * 2;   // 1 MB
    unsigned short* Wt_lo  = (unsigned short*)p; p += (size_t)HH * CC * CC * 2;
    float* d4   = (float*)p;  p += (size_t)BB * CC * 4;        // 64 KB
    float* e4   = (float*)p;  p += (size_t)HH * BB * CC * 4;   // 512 KB
    float* atts = (float*)p;  p += (size_t)HH * BB * SS * 4;   // 1 MB
    float* vs   = (float*)p;  p += (size_t)BB * HH * CC * 4;   // 512 KB

    p_trans  <<<dim3(192),          256, 0, stream>>>(w1, wv, W,
                                       w1t_hi, w1t_lo, wvt_hi, wvt_lo, Wt_hi, Wt_lo);
    k2a_d4   <<<dim3(CC/64),        256, 0, stream>>>(d1, w1, b1, d4);
    k2b_e4   <<<dim3(CC/64, HH),    256, 0, stream>>>(d4, W, e4);
    k1a_d3   <<<dim3(SS),           256, 0, stream>>>(d2, w1t_hi, w1t_lo, b1, d3_hi, d3_lo);
    k1b_tv   <<<dim3(SS),           256, 0, stream>>>(d2, wvt_hi, wvt_lo, tv);
    k3_atts  <<<dim3(SS, HH),       256, 0, stream>>>(d3_hi, d3_lo, Wt_hi, Wt_lo,
                                       e4, P, atts);
    k4_softmax<<<dim3(HH*BB),       256, 0, stream>>>(atts);
    k5_vs    <<<dim3(BB, 4),        256, 0, stream>>>(atts, tv, vs);
    k6_out   <<<dim3(128/64),       256, 0, stream>>>(vs, wcc, bcc, out);
}

// Round 6
// 370.233 us; speedup vs baseline: 5.4212x; 1.4384x over previous
//
#include <hip/hip_runtime.h>
#include <cstddef>
#include <cstdint>

// Problem constants
#define HH 8
#define FF 512
#define CC 256
#define SS 512
#define BB 64
#define SB (SS*BB)   // 32768

typedef __attribute__((ext_vector_type(4))) float f32x4;
typedef __attribute__((ext_vector_type(8))) short bf16x8;

__device__ __forceinline__ float fast_tanh(float x) {
    float e = __expf(2.0f * x);
    return 1.0f - 2.0f / (e + 1.0f);
}
__device__ __forceinline__ float relu_f(float x) { return fmaxf(x, 0.0f); }

__device__ __forceinline__ unsigned short f2bf(float x) {
    unsigned u = __float_as_uint(x);
    unsigned r = u + 0x7FFFu + ((u >> 16) & 1u);
    return (unsigned short)(r >> 16);
}
__device__ __forceinline__ float bf2f(unsigned short h) {
    return __uint_as_float(((unsigned)h) << 16);
}

// ---------------------------------------------------------------------------
// PREP: bid<192: tiled transpose+split of w1/wv ([256][512] hi/lo) and
//       W[h] rows 0..C-1 ([h][256][256] hi/lo).
//       bid 192..195: d4 = relu(d1@w1+b1) (fp32, 64x64 tile each).
// ---------------------------------------------------------------------------
__global__ __launch_bounds__(256) void p_prep(
    const float* __restrict__ w1, const float* __restrict__ wv,
    const float* __restrict__ W, const float* __restrict__ d1,
    const float* __restrict__ b1,
    unsigned short* __restrict__ w1t_hi, unsigned short* __restrict__ w1t_lo,
    unsigned short* __restrict__ wvt_hi, unsigned short* __restrict__ wvt_lo,
    unsigned short* __restrict__ Wt_hi, unsigned short* __restrict__ Wt_lo,
    float* __restrict__ d4)
{
    __shared__ float T[64][65];
    __shared__ float As[16][68];
    __shared__ float Bs[16][68];
    const int tid = threadIdx.x;
    const int bid = blockIdx.x;
    if (bid < 192) {
        const float* src;
        unsigned short *dhi, *dlo;
        int K, kt, nt;
        if (bid < 64) {
            int m = bid >> 5;            // 0: w1, 1: wv
            int t = bid & 31;
            kt = t >> 2; nt = t & 3; K = FF;
            src = m ? wv : w1;
            dhi = m ? wvt_hi : w1t_hi;
            dlo = m ? wvt_lo : w1t_lo;
        } else {
            int t = bid - 64;
            int h = t >> 4; int tt = t & 15;
            kt = tt >> 2; nt = tt & 3; K = CC;
            src = W + (size_t)h * 2 * CC * CC;
            dhi = Wt_hi + (size_t)h * CC * CC;
            dlo = Wt_lo + (size_t)h * CC * CC;
        }
        const int k0 = kt * 64, n0 = nt * 64;
        #pragma unroll
        for (int jj = 0; jj < 4; ++jj) {
            int i = (tid >> 4) + jj * 16;
            int j = (tid & 15) * 4;
            float4 v = *(const float4*)(src + (size_t)(k0 + i) * CC + n0 + j);
            T[i][j] = v.x; T[i][j+1] = v.y; T[i][j+2] = v.z; T[i][j+3] = v.w;
        }
        __syncthreads();
        #pragma unroll
        for (int jj = 0; jj < 4; ++jj) {
            int n = (tid >> 4) + jj * 16;
            int kq = (tid & 15) * 4;
            unsigned short hv[4], lv[4];
            #pragma unroll
            for (int q = 0; q < 4; ++q) {
                float x = T[kq + q][n];
                unsigned short hx = f2bf(x);
                hv[q] = hx; lv[q] = f2bf(x - bf2f(hx));
            }
            size_t o = (size_t)(n0 + n) * K + k0 + kq;
            *(ushort4*)(dhi + o) = *(ushort4*)hv;
            *(ushort4*)(dlo + o) = *(ushort4*)lv;
        }
    } else {
        // d4 tile: 64 rows x 64 cols (n0), fp32 vector GEMM
        const int n0 = (bid - 192) * 64;
        const int tx = tid & 15, ty = tid >> 4;
        const int lm = tid >> 2, lk4 = (tid & 3) * 4;
        const int bk = tid >> 4, bn4 = (tid & 15) * 4;
        float acc[4][4] = {};
        for (int k0 = 0; k0 < FF; k0 += 16) {
            float4 a = *(const float4*)(d1 + (size_t)lm * FF + k0 + lk4);
            As[lk4+0][lm] = a.x; As[lk4+1][lm] = a.y;
            As[lk4+2][lm] = a.z; As[lk4+3][lm] = a.w;
            *(float4*)&Bs[bk][bn4] = *(const float4*)(w1 + (size_t)(k0+bk)*CC + n0 + bn4);
            __syncthreads();
            #pragma unroll
            for (int kk = 0; kk < 16; ++kk) {
                float4 a4 = *(const float4*)&As[kk][ty*4];
                float4 b4 = *(const float4*)&Bs[kk][tx*4];
                float av[4] = {a4.x, a4.y, a4.z, a4.w};
                float bv[4] = {b4.x, b4.y, b4.z, b4.w};
                #pragma unroll
                for (int i = 0; i < 4; ++i)
                    #pragma unroll
                    for (int j = 0; j < 4; ++j)
                        acc[i][j] = fmaf(av[i], bv[j], acc[i][j]);
            }
            __syncthreads();
        }
        #pragma unroll
        for (int i = 0; i < 4; ++i) {
            int row = ty*4 + i;
            #pragma unroll
            for (int j = 0; j < 4; ++j)
                d4[(size_t)row*CC + n0 + tx*4 + j] = relu_f(acc[i][j] + b1[n0 + tx*4 + j]);
        }
    }
}

// ---------------------------------------------------------------------------
// K1: unified.  bid<512: 128-row x 256-col MFMA GEMM over d2 (K=512),
//   path = bid>>8: 0 -> d3 = relu(.@w1+b1) split hi/lo, 1 -> tv = tanh(.@wv).
//   4 waves of 64 rows x 128 cols. A (d2) split to LDS; B streamed via LDS.
// bid>=512: e4[h, ntile] fp32 GEMM (d4 @ W[h][C:]), LDS aliased onto A bufs.
// ---------------------------------------------------------------------------
__global__ __launch_bounds__(256, 2) void k1_main(
    const float* __restrict__ d2,
    const unsigned short* __restrict__ w1t_hi, const unsigned short* __restrict__ w1t_lo,
    const unsigned short* __restrict__ wvt_hi, const unsigned short* __restrict__ wvt_lo,
    const float* __restrict__ b1,
    const float* __restrict__ d4, const float* __restrict__ W,
    unsigned short* __restrict__ d3_hi, unsigned short* __restrict__ d3_lo,
    unsigned short* __restrict__ tv, float* __restrict__ e4)
{
    __shared__ __align__(16) unsigned short A_hi[128][40];   // 10 KB
    __shared__ __align__(16) unsigned short A_lo[128][40];   // 10 KB
    __shared__ __align__(16) unsigned short B_hi[256][40];   // 20 KB
    __shared__ __align__(16) unsigned short B_lo[256][40];   // 20 KB

    const int tid = threadIdx.x;
    const int bid = blockIdx.x;

    if (bid >= 512) {
        // ---- e4 path (fp32 vector, tiny). Alias LDS onto A buffers. ----
        float (*As)[68] = (float(*)[68])&A_hi[0][0];
        float (*Bs)[68] = (float(*)[68])&A_lo[0][0];
        const int idx = bid - 512;
        const int n0 = (idx & 3) * 64;
        const int h  = idx >> 2;
        const float* Wh = W + ((size_t)h * 2 * CC + CC) * CC;
        const int tx = tid & 15, ty = tid >> 4;
        const int lm = tid >> 2, lk4 = (tid & 3) * 4;
        const int bk = tid >> 4, bn4 = (tid & 15) * 4;
        float acc[4][4] = {};
        for (int k0 = 0; k0 < CC; k0 += 16) {
            float4 a = *(const float4*)(d4 + (size_t)lm * CC + k0 + lk4);
            As[lk4+0][lm] = a.x; As[lk4+1][lm] = a.y;
            As[lk4+2][lm] = a.z; As[lk4+3][lm] = a.w;
            *(float4*)&Bs[bk][bn4] = *(const float4*)(Wh + (size_t)(k0+bk)*CC + n0 + bn4);
            __syncthreads();
            #pragma unroll
            for (int kk = 0; kk < 16; ++kk) {
                float4 a4 = *(const float4*)&As[kk][ty*4];
                float4 b4 = *(const float4*)&Bs[kk][tx*4];
                float av[4] = {a4.x, a4.y, a4.z, a4.w};
                float bv[4] = {b4.x, b4.y, b4.z, b4.w};
                #pragma unroll
                for (int i = 0; i < 4; ++i)
                    #pragma unroll
                    for (int j = 0; j < 4; ++j)
                        acc[i][j] = fmaf(av[i], bv[j], acc[i][j]);
            }
            __syncthreads();
        }
        #pragma unroll
        for (int i = 0; i < 4; ++i) {
            int b = ty*4 + i;
            #pragma unroll
            for (int j = 0; j < 4; ++j)
                e4[((size_t)h*BB + b)*CC + n0 + tx*4 + j] = acc[i][j];
        }
        return;
    }

    // ---- main GEMM path ----
    const int path = bid >> 8;              // 0: w1->d3, 1: wv->tv
    const int r0 = (bid & 255) * 128;
    const int lane = tid & 63, w = tid >> 6;
    const int rowgrp = w & 1, colgrp = w >> 1;
    const int cb = lane & 15, quad = lane >> 4;
    const unsigned short* BH = path ? wvt_hi : w1t_hi;
    const unsigned short* BL = path ? wvt_lo : w1t_lo;

    f32x4 acc[4][8];
    f32x4 zero = {0.0f, 0.0f, 0.0f, 0.0f};
    #pragma unroll
    for (int rt = 0; rt < 4; ++rt)
        #pragma unroll
        for (int ct = 0; ct < 8; ++ct) acc[rt][ct] = zero;

    const int ar = tid >> 1, ak = (tid & 1) * 16;   // A staging coords

    for (int k0 = 0; k0 < FF; k0 += 32) {
        // stage A: 128 rows x 32 k of d2, fp32 -> hi/lo split
        {
            const float* src = d2 + (size_t)(r0 + ar) * FF + k0 + ak;
            float v[16];
            *(float4*)&v[0]  = *(const float4*)(src);
            *(float4*)&v[4]  = *(const float4*)(src + 4);
            *(float4*)&v[8]  = *(const float4*)(src + 8);
            *(float4*)&v[12] = *(const float4*)(src + 12);
            bf16x8 vh0, vh1, vl0, vl1;
            #pragma unroll
            for (int j = 0; j < 8; ++j) {
                unsigned short h = f2bf(v[j]);
                vh0[j] = (short)h; vl0[j] = (short)f2bf(v[j] - bf2f(h));
                unsigned short h2 = f2bf(v[j+8]);
                vh1[j] = (short)h2; vl1[j] = (short)f2bf(v[j+8] - bf2f(h2));
            }
            *(bf16x8*)&A_hi[ar][ak]     = vh0;
            *(bf16x8*)&A_hi[ar][ak + 8] = vh1;
            *(bf16x8*)&A_lo[ar][ak]     = vl0;
            *(bf16x8*)&A_lo[ar][ak + 8] = vl1;
        }
        // stage B: 256 n x 32 k
        #pragma unroll
        for (int j = 0; j < 4; ++j) {
            int idx = j * 256 + tid;
            int n = idx >> 2, kp = (idx & 3) * 8;
            *(bf16x8*)&B_hi[n][kp] = *(const bf16x8*)(BH + (size_t)n * FF + k0 + kp);
            *(bf16x8*)&B_lo[n][kp] = *(const bf16x8*)(BL + (size_t)n * FF + k0 + kp);
        }
        __syncthreads();
        bf16x8 ahf[4], alf[4];
        #pragma unroll
        for (int rt = 0; rt < 4; ++rt) {
            ahf[rt] = *(bf16x8*)&A_hi[rowgrp*64 + rt*16 + cb][quad*8];
            alf[rt] = *(bf16x8*)&A_lo[rowgrp*64 + rt*16 + cb][quad*8];
        }
        #pragma unroll
        for (int ct = 0; ct < 8; ++ct) {
            bf16x8 bh = *(bf16x8*)&B_hi[colgrp*128 + ct*16 + cb][quad*8];
            bf16x8 bl = *(bf16x8*)&B_lo[colgrp*128 + ct*16 + cb][quad*8];
            #pragma unroll
            for (int rt = 0; rt < 4; ++rt) {
                acc[rt][ct] = __builtin_amdgcn_mfma_f32_16x16x32_bf16(ahf[rt], bh, acc[rt][ct], 0, 0, 0);
                acc[rt][ct] = __builtin_amdgcn_mfma_f32_16x16x32_bf16(ahf[rt], bl, acc[rt][ct], 0, 0, 0);
                acc[rt][ct] = __builtin_amdgcn_mfma_f32_16x16x32_bf16(alf[rt], bh, acc[rt][ct], 0, 0, 0);
            }
        }
        __syncthreads();
    }
    // epilogue. C layout: col = ct*16+cb (+colgrp*128), row = rt*16+quad*4+reg (+rowgrp*64)
    if (path == 0) {
        float bias[8];
        #pragma unroll
        for (int ct = 0; ct < 8; ++ct) bias[ct] = b1[colgrp*128 + ct*16 + cb];
        #pragma unroll
        for (int rt = 0; rt < 4; ++rt) {
            #pragma unroll
            for (int r = 0; r < 4; ++r) {
                int gr = r0 + rowgrp*64 + rt*16 + quad*4 + r;
                #pragma unroll
                for (int ct = 0; ct < 8; ++ct) {
                    int c = colgrp*128 + ct*16 + cb;
                    float val = relu_f(acc[rt][ct][r] + bias[ct]);
                    unsigned short hv = f2bf(val);
                    d3_hi[(size_t)gr * CC + c] = hv;
                    d3_lo[(size_t)gr * CC + c] = f2bf(val - bf2f(hv));
                }
            }
        }
    } else {
        #pragma unroll
        for (int rt = 0; rt < 4; ++rt) {
            #pragma unroll
            for (int r = 0; r < 4; ++r) {
                int gr = r0 + rowgrp*64 + rt*16 + quad*4 + r;
                int s = gr >> 6, b = gr & 63;
                #pragma unroll
                for (int ct = 0; ct < 8; ++ct) {
                    int c = colgrp*128 + ct*16 + cb;
                    tv[((size_t)b * SS + s) * CC + c] = f2bf(fast_tanh(acc[rt][ct][r]));
                }
            }
        }
    }
}

// ---------------------------------------------------------------------------
// K3: atts[h,b,s] = sum_c P[h,c]*tanh((d3@Wt[h])[row,c] + e4[h,b,c]).
// Block: 128 rows (2 s) x 256 cols, one head. 4 waves of 64x128. A+B in LDS.
// ---------------------------------------------------------------------------
__global__ __launch_bounds__(256, 2) void k3_atts(
    const unsigned short* __restrict__ d3_hi, const unsigned short* __restrict__ d3_lo,
    const unsigned short* __restrict__ Wt_hi, const unsigned short* __restrict__ Wt_lo,
    const float* __restrict__ e4, const float* __restrict__ P,
    float* __restrict__ atts)
{
    __shared__ __align__(16) unsigned short A_hi[128][40];
    __shared__ __align__(16) unsigned short A_lo[128][40];
    __shared__ __align__(16) unsigned short B_hi[256][40];
    __shared__ __align__(16) unsigned short B_lo[256][40];
    __shared__ float red[2][128];

    const int tid = threadIdx.x;
    const int lane = tid & 63, w = tid >> 6;
    const int h = blockIdx.y;
    const int r0 = blockIdx.x * 128;
    const int rowgrp = w & 1, colgrp = w >> 1;
    const int cb = lane & 15, quad = lane >> 4;

    const unsigned short* WhH = Wt_hi + (size_t)h * CC * CC;
    const unsigned short* WhL = Wt_lo + (size_t)h * CC * CC;

    f32x4 acc[4][8];
    f32x4 zero = {0.0f, 0.0f, 0.0f, 0.0f};
    #pragma unroll
    for (int rt = 0; rt < 4; ++rt)
        #pragma unroll
        for (int ct = 0; ct < 8; ++ct) acc[rt][ct] = zero;

    const int ar = tid >> 1, ak = (tid & 1) * 16;

    for (int k0 = 0; k0 < CC; k0 += 32) {
        *(bf16x8*)&A_hi[ar][ak]     = *(const bf16x8*)(d3_hi + (size_t)(r0 + ar) * CC + k0 + ak);
        *(bf16x8*)&A_hi[ar][ak + 8] = *(const bf16x8*)(d3_hi + (size_t)(r0 + ar) * CC + k0 + ak + 8);
        *(bf16x8*)&A_lo[ar][ak]     = *(const bf16x8*)(d3_lo + (size_t)(r0 + ar) * CC + k0 + ak);
        *(bf16x8*)&A_lo[ar][ak + 8] = *(const bf16x8*)(d3_lo + (size_t)(r0 + ar) * CC + k0 + ak + 8);
        #pragma unroll
        for (int j = 0; j < 4; ++j) {
            int idx = j * 256 + tid;
            int n = idx >> 2, kp = (idx & 3) * 8;
            *(bf16x8*)&B_hi[n][kp] = *(const bf16x8*)(WhH + (size_t)n * CC + k0 + kp);
            *(bf16x8*)&B_lo[n][kp] = *(const bf16x8*)(WhL + (size_t)n * CC + k0 + kp);
        }
        __syncthreads();
        bf16x8 ahf[4], alf[4];
        #pragma unroll
        for (int rt = 0; rt < 4; ++rt) {
            ahf[rt] = *(bf16x8*)&A_hi[rowgrp*64 + rt*16 + cb][quad*8];
            alf[rt] = *(bf16x8*)&A_lo[rowgrp*64 + rt*16 + cb][quad*8];
        }
        #pragma unroll
        for (int ct = 0; ct < 8; ++ct) {
            bf16x8 bh = *(bf16x8*)&B_hi[colgrp*128 + ct*16 + cb][quad*8];
            bf16x8 bl = *(bf16x8*)&B_lo[colgrp*128 + ct*16 + cb][quad*8];
            #pragma unroll
            for (int rt = 0; rt < 4; ++rt) {
                acc[rt][ct] = __builtin_amdgcn_mfma_f32_16x16x32_bf16(ahf[rt], bh, acc[rt][ct], 0, 0, 0);
                acc[rt][ct] = __builtin_amdgcn_mfma_f32_16x16x32_bf16(ahf[rt], bl, acc[rt][ct], 0, 0, 0);
                acc[rt][ct] = __builtin_amdgcn_mfma_f32_16x16x32_bf16(alf[rt], bh, acc[rt][ct], 0, 0, 0);
            }
        }
        __syncthreads();
    }
    // epilogue: tanh + P-dot over this wave's 128 cols, then reduce
    float Pv[8];
    #pragma unroll
    for (int ct = 0; ct < 8; ++ct) Pv[ct] = P[(size_t)h * CC + colgrp*128 + ct*16 + cb];
    #pragma unroll
    for (int rt = 0; rt < 4; ++rt) {
        #pragma unroll
        for (int r = 0; r < 4; ++r) {
            int b = rt*16 + quad*4 + r;     // batch index (mod 64)
            const float* e4p = e4 + ((size_t)h * BB + b) * CC + colgrp*128 + cb;
            float part = 0.0f;
            #pragma unroll
            for (int ct = 0; ct < 8; ++ct) {
                float u = acc[rt][ct][r] + e4p[ct*16];
                part = fmaf(Pv[ct], fast_tanh(u), part);
            }
            part += __shfl_xor(part, 1); part += __shfl_xor(part, 2);
            part += __shfl_xor(part, 4); part += __shfl_xor(part, 8);
            if (cb == 0) red[colgrp][rowgrp*64 + b] = part;
        }
    }
    __syncthreads();
    if (tid < 128) {
        float v = red[0][tid] + red[1][tid];
        int gr = r0 + tid;
        int s = gr >> 6, b = gr & 63;
        atts[((size_t)h * BB + b) * SS + s] = v;
    }
}

// ---------------------------------------------------------------------------
// K456: per b: softmax over s (8 heads) + vs = scores.tv + out = relu(vs@wcc+bcc)
// ---------------------------------------------------------------------------
__global__ __launch_bounds__(256) void k456_out(
    const float* __restrict__ atts, const unsigned short* __restrict__ tv,
    const float* __restrict__ wcc, const float* __restrict__ bcc,
    float* __restrict__ out)
{
    __shared__ float sc[HH][SS];       // 16 KB
    __shared__ float red[4][2048];     // 32 KB
    const int b = blockIdx.x;
    const int tid = threadIdx.x;
    const int lane = tid & 63, w = tid >> 6;

    for (int i = tid; i < HH*SS; i += 256) {
        int h = i >> 9, s = i & 511;
        sc[h][s] = atts[((size_t)h*BB + b)*SS + s];
    }
    __syncthreads();
    // softmax: wave w handles heads 2w, 2w+1
    #pragma unroll
    for (int t = 0; t < 2; ++t) {
        int hh = w*2 + t;
        float x[8];
        #pragma unroll
        for (int j = 0; j < 8; ++j) x[j] = sc[hh][j*64 + lane];
        float m = x[0];
        #pragma unroll
        for (int j = 1; j < 8; ++j) m = fmaxf(m, x[j]);
        #pragma unroll
        for (int d = 1; d < 64; d <<= 1) m = fmaxf(m, __shfl_xor(m, d));
        float sum = 0.0f;
        #pragma unroll
        for (int j = 0; j < 8; ++j) { x[j] = __expf(x[j] - m); sum += x[j]; }
        #pragma unroll
        for (int d = 1; d < 64; d <<= 1) sum += __shfl_xor(sum, d);
        float inv = 1.0f / sum;
        #pragma unroll
        for (int j = 0; j < 8; ++j) sc[hh][j*64 + lane] = x[j] * inv;
    }
    __syncthreads();
    // vs: stripe = s-range of 128, each lane owns 4 c
    {
        const int cl = tid & 63, stripe = tid >> 6;
        const int c0 = cl * 4;
        const unsigned short* tvb = tv + ((size_t)b * SS + stripe * 128) * CC + c0;
        float acc[HH][4] = {};
        for (int si = 0; si < 128; ++si) {
            uint2 u = *(const uint2*)(tvb + (size_t)si * CC);
            float x0 = bf2f((unsigned short)(u.x));
            float x1 = bf2f((unsigned short)(u.x >> 16));
            float x2 = bf2f((unsigned short)(u.y));
            float x3 = bf2f((unsigned short)(u.y >> 16));
            int s = stripe * 128 + si;
            #pragma unroll
            for (int h = 0; h < HH; ++h) {
                float wgt = sc[h][s];
                acc[h][0] = fmaf(wgt, x0, acc[h][0]);
                acc[h][1] = fmaf(wgt, x1, acc[h][1]);
                acc[h][2] = fmaf(wgt, x2, acc[h][2]);
                acc[h][3] = fmaf(wgt, x3, acc[h][3]);
            }
        }
        #pragma unroll
        for (int h = 0; h < HH; ++h)
            #pragma unroll
            for (int j = 0; j < 4; ++j)
                red[stripe][h*256 + c0 + j] = acc[h][j];
    }
    __syncthreads();
    for (int i = tid; i < 2048; i += 256)
        red[0][i] = red[0][i] + red[1][i] + red[2][i] + red[3][i];
    __syncthreads();
    // out: 2 threads per output column
    {
        const int n = tid & 127, half = tid >> 7;
        float o = 0.0f;
        const int kbase = half * 1024;
        for (int k = 0; k < 1024; ++k)
            o = fmaf(red[0][kbase + k], wcc[(size_t)(kbase + k) * 128 + n], o);
        float* r2 = &sc[0][0];
        r2[half * 128 + n] = o;
    }
    __syncthreads();
    if (tid < 128)
        out[(size_t)b * 128 + tid] = relu_f(sc[0][tid] + sc[0][128 + tid] + bcc[tid]);
}

// ---------------------------------------------------------------------------
extern "C" void kernel_launch(void* const* d_in, const int* in_sizes, int n_in,
                              void* d_out, int out_size, void* d_ws, size_t ws_size,
                              hipStream_t stream)
{
    (void)in_sizes; (void)n_in; (void)out_size; (void)ws_size;
    const float* d1  = (const float*)d_in[0];
    const float* d2  = (const float*)d_in[1];
    const float* w1  = (const float*)d_in[2];
    const float* b1  = (const float*)d_in[3];
    const float* W   = (const float*)d_in[4];
    const float* P   = (const float*)d_in[5];
    const float* wv  = (const float*)d_in[6];
    const float* wcc = (const float*)d_in[7];
    const float* bcc = (const float*)d_in[8];
    float* out = (float*)d_out;

    char* p = (char*)d_ws;
    unsigned short* d3_hi = (unsigned short*)p;  p += (size_t)SB * CC * 2;
    unsigned short* d3_lo = (unsigned short*)p;  p += (size_t)SB * CC * 2;
    unsigned short* tv    = (unsigned short*)p;  p += (size_t)BB * SS * CC * 2;
    unsigned short* w1t_hi = (unsigned short*)p; p += (size_t)CC * FF * 2;
    unsigned short* w1t_lo = (unsigned short*)p; p += (size_t)CC * FF * 2;
    unsigned short* wvt_hi = (unsigned short*)p; p += (size_t)CC * FF * 2;
    unsigned short* wvt_lo = (unsigned short*)p; p += (size_t)CC * FF * 2;
    unsigned short* Wt_hi  = (unsigned short*)p; p += (size_t)HH * CC * CC * 2;
    unsigned short* Wt_lo  = (unsigned short*)p; p += (size_t)HH * CC * CC * 2;
    float* d4   = (float*)p;  p += (size_t)BB * CC * 4;
    float* e4   = (float*)p;  p += (size_t)HH * BB * CC * 4;
    float* atts = (float*)p;  p += (size_t)HH * BB * SS * 4;

    p_prep   <<<dim3(196),       256, 0, stream>>>(w1, wv, W, d1, b1,
                  w1t_hi, w1t_lo, wvt_hi, wvt_lo, Wt_hi, Wt_lo, d4);
    k1_main  <<<dim3(544),       256, 0, stream>>>(d2, w1t_hi, w1t_lo,
                  wvt_hi, wvt_lo, b1, d4, W, d3_hi, d3_lo, tv, e4);
    k3_atts  <<<dim3(256, HH),   256, 0, stream>>>(d3_hi, d3_lo, Wt_hi, Wt_lo,
                  e4, P, atts);
    k456_out <<<dim3(BB),        256, 0, stream>>>(atts, tv, wcc, bcc, out);
}